// Round 2
// baseline (555.719 us; speedup 1.0000x reference)
//
#include <hip/hip_runtime.h>

#define NN 8192
#define NHID 64
#define NCLASS 8
#define NEDGE (NN * 32)   // 262144

typedef __attribute__((ext_vector_type(8))) short bf16x8_t;
typedef __attribute__((ext_vector_type(4))) float f32x4_t;

__device__ __forceinline__ unsigned short f2bf(float f) {
    unsigned int u = __float_as_uint(f);
    u += 0x7FFF + ((u >> 16) & 1);   // round-to-nearest-even
    return (unsigned short)(u >> 16);
}

// ---------------- W1 -> bf16 transposed [64][8192] ----------------
__global__ __launch_bounds__(256) void w1t_kernel(const float* __restrict__ W1,
                                                  unsigned short* __restrict__ w1t) {
    const int idx = blockIdx.x * 256 + threadIdx.x;   // 0 .. 64*8192-1
    const int n = idx >> 13;          // 0..63
    const int k = idx & (NN - 1);     // 0..8191
    w1t[idx] = f2bf(W1[(size_t)k * NHID + n]);  // coalesced writes, L2-cached strided reads
}

// ---------------- CSR build ----------------
__global__ __launch_bounds__(256) void hist_kernel(const int* __restrict__ row,
                                                   int* __restrict__ counts) {
    const int e = blockIdx.x * 256 + threadIdx.x;
    if (e < NEDGE) atomicAdd(&counts[row[e]], 1);
}

__global__ __launch_bounds__(1024) void scan_kernel(const int* __restrict__ counts,
                                                    int* __restrict__ row_start,
                                                    int* __restrict__ row_fill) {
    __shared__ int sdata[1024];
    const int tid = threadIdx.x;
    int loc[8];
    int t = 0;
#pragma unroll
    for (int j = 0; j < 8; ++j) { loc[j] = counts[tid * 8 + j]; t += loc[j]; }
    sdata[tid] = t;
    __syncthreads();
    for (int off = 1; off < 1024; off <<= 1) {
        const int add = (tid >= off) ? sdata[tid - off] : 0;
        __syncthreads();
        sdata[tid] += add;
        __syncthreads();
    }
    int excl = sdata[tid] - t;   // exclusive prefix
#pragma unroll
    for (int j = 0; j < 8; ++j) {
        row_start[tid * 8 + j] = excl;
        row_fill[tid * 8 + j] = excl;
        excl += loc[j];
    }
    if (tid == 1023) row_start[NN] = excl;   // == NEDGE
}

__global__ __launch_bounds__(256) void scatter_kernel(const int* __restrict__ row,
                                                      const int* __restrict__ col,
                                                      const float* __restrict__ val,
                                                      int* __restrict__ row_fill,
                                                      int* __restrict__ ccol,
                                                      float* __restrict__ cval) {
    const int e = blockIdx.x * 256 + threadIdx.x;
    if (e >= NEDGE) return;
    const int pos = atomicAdd(&row_fill[row[e]], 1);
    ccol[pos] = col[e];
    cval[pos] = val[e];
}

// ---------------- GEMM1: support1 = x @ W1  (bf16 MFMA, split-K atomics) ----
// grid (64, 8), block 256.  BM=128, BK=64, K-split = 1024 each.
__global__ __launch_bounds__(256, 2) void gemm1_kernel(const float* __restrict__ x,
                                                       const unsigned short* __restrict__ w1t,
                                                       float* __restrict__ outp) {
    __shared__ short As[128][72];   // row-major tile, padded (144B rows, 16B aligned)
    __shared__ short Bs[64][72];    // Bs[n][k]
    const int tid = threadIdx.x;
    const int r0 = blockIdx.x * 128;
    const int k0base = blockIdx.y * (NN / 8);
    const int lane = tid & 63;
    const int wv = tid >> 6;
    const int m16 = lane & 15;
    const int quad = lane >> 4;
    const int c4 = tid & 15;
    const int rA = tid >> 4;

    f32x4_t acc[2][4];
#pragma unroll
    for (int i = 0; i < 2; ++i)
#pragma unroll
        for (int j = 0; j < 4; ++j) acc[i][j] = (f32x4_t){0.f, 0.f, 0.f, 0.f};

    for (int kt = 0; kt < (NN / 8) / 64; ++kt) {
        const int k0 = k0base + kt * 64;
        // stage A: 128 rows x 64 k, fp32 -> bf16
#pragma unroll
        for (int i = 0; i < 8; ++i) {
            const int r = rA + i * 16;
            const float4 v = *(const float4*)(x + (size_t)(r0 + r) * NN + k0 + c4 * 4);
            *(ushort4*)(&As[r][c4 * 4]) =
                make_ushort4(f2bf(v.x), f2bf(v.y), f2bf(v.z), f2bf(v.w));
        }
        // stage B: 64 n-rows x 64 k bf16 (already transposed in global)
#pragma unroll
        for (int it = 0; it < 2; ++it) {
            const int idx = tid + it * 256;
            const int n = idx >> 3;
            const int kc = idx & 7;
            *(uint4*)(&Bs[n][kc * 8]) = *(const uint4*)(w1t + (size_t)n * NN + k0 + kc * 8);
        }
        __syncthreads();
#pragma unroll
        for (int kk = 0; kk < 64; kk += 32) {
            bf16x8_t af[2], bfr[4];
#pragma unroll
            for (int rt = 0; rt < 2; ++rt)
                af[rt] = *(const bf16x8_t*)(&As[wv * 32 + rt * 16 + m16][kk + quad * 8]);
#pragma unroll
            for (int ct = 0; ct < 4; ++ct)
                bfr[ct] = *(const bf16x8_t*)(&Bs[ct * 16 + m16][kk + quad * 8]);
#pragma unroll
            for (int rt = 0; rt < 2; ++rt)
#pragma unroll
                for (int ct = 0; ct < 4; ++ct)
                    acc[rt][ct] = __builtin_amdgcn_mfma_f32_16x16x32_bf16(
                        af[rt], bfr[ct], acc[rt][ct], 0, 0, 0);
        }
        __syncthreads();
    }
    // epilogue: atomic split-K accumulate; C/D: col=lane&15, row=quad*4+reg
#pragma unroll
    for (int rt = 0; rt < 2; ++rt)
#pragma unroll
        for (int ct = 0; ct < 4; ++ct)
#pragma unroll
            for (int reg = 0; reg < 4; ++reg) {
                const int row = r0 + wv * 32 + rt * 16 + quad * 4 + reg;
                const int col = ct * 16 + m16;
                atomicAdd(&outp[(size_t)row * NHID + col], acc[rt][ct][reg]);
            }
}

// ---------------- SpMM (CSR, one wave per dest row, lane = feature) --------
__global__ __launch_bounds__(256) void spmm64_kernel(const float* __restrict__ sup,
                                                     const int* __restrict__ row_start,
                                                     const int* __restrict__ ccol,
                                                     const float* __restrict__ cval,
                                                     const float* __restrict__ bias,
                                                     float* __restrict__ outp,
                                                     const int do_relu) {
    const int wid = (blockIdx.x * 256 + threadIdx.x) >> 6;   // dest row
    const int lane = threadIdx.x & 63;
    const int s = row_start[wid];
    const int e = row_start[wid + 1];
    float acc = 0.f;
    for (int i = s; i < e; ++i) {
        const int c = ccol[i];
        const float v = cval[i];
        acc = fmaf(v, sup[(size_t)c * NHID + lane], acc);
    }
    acc += bias[lane];
    if (do_relu) acc = fmaxf(acc, 0.f);
    outp[(size_t)wid * NHID + lane] = acc;
}

__global__ __launch_bounds__(256) void spmm8_kernel(const float* __restrict__ sup,
                                                    const int* __restrict__ row_start,
                                                    const int* __restrict__ ccol,
                                                    const float* __restrict__ cval,
                                                    const float* __restrict__ bias,
                                                    float* __restrict__ outp) {
    const int gid = blockIdx.x * 256 + threadIdx.x;
    const int r = gid >> 3;
    const int c = gid & 7;
    const int s = row_start[r];
    const int e = row_start[r + 1];
    float acc = 0.f;
    for (int i = s; i < e; ++i)
        acc = fmaf(cval[i], sup[(size_t)ccol[i] * NCLASS + c], acc);
    outp[(size_t)r * NCLASS + c] = acc + bias[c];
}

// ---------------- GEMM2: support2 = h1 @ W2  (fp32, W2 in LDS) -------------
__global__ __launch_bounds__(256) void gemm2_kernel(const float* __restrict__ h,
                                                    const float* __restrict__ W,
                                                    float* __restrict__ outp) {
    __shared__ float Ws[NHID * NHID];
    for (int i = threadIdx.x; i < NHID * NHID; i += 256) Ws[i] = W[i];
    __syncthreads();
    const int lane = threadIdx.x & 63;
    const int wv = threadIdx.x >> 6;
    const int rbase = blockIdx.x * 32 + wv * 8;
    for (int rr = 0; rr < 8; ++rr) {
        const int r = rbase + rr;
        const float hval = h[(size_t)r * NHID + lane];
        float acc = 0.f;
#pragma unroll
        for (int k = 0; k < NHID; ++k)
            acc = fmaf(__shfl(hval, k, 64), Ws[k * NHID + lane], acc);
        outp[(size_t)r * NHID + lane] = acc;
    }
}

// ---------------- GEMM3: support3 = h2 @ W3  (fp32) ------------------------
__global__ __launch_bounds__(256) void gemm3_kernel(const float* __restrict__ h,
                                                    const float* __restrict__ W,
                                                    float* __restrict__ outp) {
    __shared__ float Ws[NHID * NCLASS];
    // BUGFIX round 2: NHID*NCLASS = 512 > blockDim 256; previous code staged
    // only the first 256 elements, leaving W3 rows 32..63 as garbage LDS.
    for (int i = threadIdx.x; i < NHID * NCLASS; i += 256) Ws[i] = W[i];
    __syncthreads();
    const int gid = blockIdx.x * 256 + threadIdx.x;
    const int r = gid >> 3;
    const int c = gid & 7;
    const float* hr = h + (size_t)r * NHID;
    float acc = 0.f;
#pragma unroll
    for (int k4 = 0; k4 < NHID / 4; ++k4) {
        const float4 hv = *(const float4*)(hr + k4 * 4);
        acc = fmaf(hv.x, Ws[(k4 * 4 + 0) * NCLASS + c], acc);
        acc = fmaf(hv.y, Ws[(k4 * 4 + 1) * NCLASS + c], acc);
        acc = fmaf(hv.z, Ws[(k4 * 4 + 2) * NCLASS + c], acc);
        acc = fmaf(hv.w, Ws[(k4 * 4 + 3) * NCLASS + c], acc);
    }
    outp[(size_t)r * NCLASS + c] = acc;
}

// ---------------- log_softmax over 8 classes, in place ---------------------
__global__ __launch_bounds__(256) void lsm_kernel(float* __restrict__ h) {
    const int r = blockIdx.x * 256 + threadIdx.x;
    float4 a = *(float4*)(h + (size_t)r * 8);
    float4 b = *(float4*)(h + (size_t)r * 8 + 4);
    const float m = fmaxf(fmaxf(fmaxf(a.x, a.y), fmaxf(a.z, a.w)),
                          fmaxf(fmaxf(b.x, b.y), fmaxf(b.z, b.w)));
    const float s = expf(a.x - m) + expf(a.y - m) + expf(a.z - m) + expf(a.w - m) +
                    expf(b.x - m) + expf(b.y - m) + expf(b.z - m) + expf(b.w - m);
    const float lse = m + logf(s);
    a.x -= lse; a.y -= lse; a.z -= lse; a.w -= lse;
    b.x -= lse; b.y -= lse; b.z -= lse; b.w -= lse;
    *(float4*)(h + (size_t)r * 8) = a;
    *(float4*)(h + (size_t)r * 8 + 4) = b;
}

// ---------------- output init + final linear -------------------------------
__global__ void init_out_kernel(float* __restrict__ outp, const float* __restrict__ blin) {
    if (threadIdx.x < NCLASS) outp[threadIdx.x] = blin[0];
}

__global__ __launch_bounds__(256) void final_kernel(const float* __restrict__ ls,
                                                    const float* __restrict__ wlin,
                                                    float* __restrict__ outp) {
    const int gid = blockIdx.x * 256 + threadIdx.x;   // one thread per node row
    const float w = wlin[gid];
    const float4 a = *(const float4*)(ls + (size_t)gid * 8);
    const float4 b = *(const float4*)(ls + (size_t)gid * 8 + 4);
    float p[8] = {a.x * w, a.y * w, a.z * w, a.w * w,
                  b.x * w, b.y * w, b.z * w, b.w * w};
#pragma unroll
    for (int off = 32; off > 0; off >>= 1) {
#pragma unroll
        for (int c = 0; c < 8; ++c) p[c] += __shfl_down(p[c], off);
    }
    if ((threadIdx.x & 63) == 0) {
#pragma unroll
        for (int c = 0; c < 8; ++c) atomicAdd(&outp[c], p[c]);
    }
}

extern "C" void kernel_launch(void* const* d_in, const int* in_sizes, int n_in,
                              void* d_out, int out_size, void* d_ws, size_t ws_size,
                              hipStream_t stream) {
    const float* x       = (const float*)d_in[0];
    const int*   adj_row = (const int*)d_in[1];
    const int*   adj_col = (const int*)d_in[2];
    const float* adj_val = (const float*)d_in[3];
    const float* W1      = (const float*)d_in[4];
    const float* b1      = (const float*)d_in[5];
    const float* W2      = (const float*)d_in[6];
    const float* b2      = (const float*)d_in[7];
    const float* W3      = (const float*)d_in[8];
    const float* b3      = (const float*)d_in[9];
    const float* Wlin    = (const float*)d_in[10];
    const float* blin    = (const float*)d_in[11];
    float* outp = (float*)d_out;

    char* ws = (char*)d_ws;
    float*          bufA      = (float*)ws;                          // 2 MB (support)
    float*          bufB      = (float*)(ws + (2u << 20));           // 2 MB (h)
    unsigned short* w1t       = (unsigned short*)(ws + (4u << 20));  // 1 MB
    int*            ccol      = (int*)(ws + (5u << 20));             // 1 MB
    float*          cval      = (float*)(ws + (6u << 20));           // 1 MB
    int*            row_start = (int*)(ws + (7u << 20));             // 32772 B
    int*            row_fill  = (int*)(ws + (7u << 20) + (64u << 10));
    int*            counts    = (int*)(ws + (7u << 20) + (128u << 10));

    hipMemsetAsync(bufA, 0, (size_t)NN * NHID * sizeof(float), stream);  // split-K accum
    hipMemsetAsync(counts, 0, (size_t)NN * sizeof(int), stream);

    init_out_kernel<<<1, 64, 0, stream>>>(outp, blin);
    w1t_kernel<<<(NHID * NN) / 256, 256, 0, stream>>>(W1, w1t);
    hist_kernel<<<NEDGE / 256, 256, 0, stream>>>(adj_row, counts);
    scan_kernel<<<1, 1024, 0, stream>>>(counts, row_start, row_fill);
    scatter_kernel<<<NEDGE / 256, 256, 0, stream>>>(adj_row, adj_col, adj_val,
                                                    row_fill, ccol, cval);
    gemm1_kernel<<<dim3(NN / 128, 8), 256, 0, stream>>>(x, w1t, bufA);
    spmm64_kernel<<<(NN * 64) / 256, 256, 0, stream>>>(bufA, row_start, ccol, cval, b1, bufB, 1);
    gemm2_kernel<<<NN / 32, 256, 0, stream>>>(bufB, W2, bufA);
    spmm64_kernel<<<(NN * 64) / 256, 256, 0, stream>>>(bufA, row_start, ccol, cval, b2, bufB, 1);
    gemm3_kernel<<<(NN * 8) / 256, 256, 0, stream>>>(bufB, W3, bufA);
    spmm8_kernel<<<(NN * 8) / 256, 256, 0, stream>>>(bufA, row_start, ccol, cval, b3, bufB);
    lsm_kernel<<<NN / 256, 256, 0, stream>>>(bufB);
    final_kernel<<<NN / 256, 256, 0, stream>>>(bufB, Wlin, outp);
}